// Round 16
// baseline (667.236 us; speedup 1.0000x reference)
//
#include <hip/hip_runtime.h>
#include <hip/hip_bf16.h>
#include <hip/hip_cooperative_groups.h>
#include <math.h>

namespace cg = cooperative_groups;

#define C 256
#define NROWS (64*56*56)   // 200704
#define EPSV 0.001f
#define TRI(i) (((i)*((i)+1))>>1)
#define NBLK 224           // k_cov blocks

typedef __attribute__((ext_vector_type(8))) short bf16x8;
typedef __attribute__((ext_vector_type(4))) float f32x4;
typedef __attribute__((ext_vector_type(4))) unsigned short u16x4;
typedef __attribute__((ext_vector_type(8))) unsigned short u16x8;
#define MFMA16 __builtin_amdgcn_mfma_f32_16x16x32_bf16

// padded packed-lower-triangle layout: row i starts at PAD(i), rows rounded to 4 floats
__device__ __forceinline__ int PAD(int i) {
    int a = i >> 2, b = i & 3;
    return ((a + 1) * (2 * a + b)) << 2;
}

__device__ __forceinline__ float bcastf(float v, int l) {
    return __int_as_float(__builtin_amdgcn_readlane(__float_as_int(v), l));
}

__device__ __forceinline__ void split2(float v0, float v1, unsigned& hi, unsigned& lo) {
    unsigned b0 = __float_as_uint(v0), b1 = __float_as_uint(v1);
    hi = (b0 >> 16) | (b1 & 0xFFFF0000u);
    float l0 = v0 - __uint_as_float(b0 & 0xFFFF0000u);
    float l1 = v1 - __uint_as_float(b1 & 0xFFFF0000u);
    lo = (__float_as_uint(l0) >> 16) | (__float_as_uint(l1) & 0xFFFF0000u);
}

// ws layout (floats):
//  [0,256)              : channel sums
//  [256,512)            : biasacc
//  [512,33792)          : Lg = triangle (cov -> factored; diag blocks := Dinv)
//  [33792,7832576)      : P  = per-block cov partials [224][8][17][256]
//  [7832576,+32768)     : Wphi (65536 bf16)
//  [7865344,+32768)     : Wplo

// ---------------- K2: S = X^T X via bf16-split MFMA, partials to P (no atomics) ----------------
template<int W>
__device__ __forceinline__ void cov_step(f32x4* acc, const unsigned* lh, const unsigned* ll,
                                         int m, int kg) {
    constexpr int R0 = W, R1 = 15 - W;
    constexpr int O1 = W + 1;
    bf16x8 ah[2], al[2];
    {
        int r0 = R0 * 16 + m, r1 = R1 * 16 + m;
        int o0 = r0 * 20 + ((kg ^ ((r0 >> 3) & 3)) << 2);
        int o1 = r1 * 20 + ((kg ^ ((r1 >> 3) & 3)) << 2);
        ah[0] = *(const bf16x8*)&lh[o0]; al[0] = *(const bf16x8*)&ll[o0];
        ah[1] = *(const bf16x8*)&lh[o1]; al[1] = *(const bf16x8*)&ll[o1];
    }
#pragma unroll
    for (int c = 0; c <= R1; ++c) {
        int rb = c * 16 + m;
        int ob = rb * 20 + ((kg ^ ((rb >> 3) & 3)) << 2);
        bf16x8 bh = *(const bf16x8*)&lh[ob];
        bf16x8 bl = *(const bf16x8*)&ll[ob];
        if (c <= R0) {
            acc[c] = MFMA16(ah[0], bh, acc[c], 0, 0, 0);
            acc[c] = MFMA16(ah[0], bl, acc[c], 0, 0, 0);
            acc[c] = MFMA16(al[0], bh, acc[c], 0, 0, 0);
        }
        {
            acc[O1 + c] = MFMA16(ah[1], bh, acc[O1 + c], 0, 0, 0);
            acc[O1 + c] = MFMA16(ah[1], bl, acc[O1 + c], 0, 0, 0);
            acc[O1 + c] = MFMA16(al[1], bh, acc[O1 + c], 0, 0, 0);
        }
    }
}

__global__ __launch_bounds__(512, 4) void k_cov(const float* __restrict__ x,
                                                float* __restrict__ P,
                                                float* __restrict__ sums) {
    __shared__ unsigned lh[256 * 20];    // 20 KB
    __shared__ unsigned ll_[256 * 20];   // 20 KB
    int tid = threadIdx.x, wave = tid >> 6, lane = tid & 63;
    int m = lane & 15, kg = lane >> 4;
    int ch = tid & 255, half = tid >> 8;
    const float* xc = x + (size_t)blockIdx.x * 896 * 256 + ch;
    f32x4 acc[17];
#pragma unroll
    for (int t = 0; t < 17; ++t) acc[t] = 0.f;
    float colsum = 0.f;
    int swkey = (ch >> 3) & 3;

    for (int it = 0; it < 28; ++it) {
        __syncthreads();
        const float* xr = xc + it * 32 * 256;
#pragma unroll
        for (int j = 0; j < 8; ++j) {
            int rp = half * 8 + j;
            float v0 = xr[(2 * rp) * 256];
            float v1 = xr[(2 * rp + 1) * 256];
            colsum += v0 + v1;
            unsigned h, l;
            split2(v0, v1, h, l);
            int idx = ch * 20 + ((((rp >> 2) ^ swkey) << 2) | (rp & 3));
            lh[idx] = h;
            ll_[idx] = l;
        }
        __syncthreads();
        switch (wave) {
            case 0: cov_step<0>(acc, lh, ll_, m, kg); break;
            case 1: cov_step<1>(acc, lh, ll_, m, kg); break;
            case 2: cov_step<2>(acc, lh, ll_, m, kg); break;
            case 3: cov_step<3>(acc, lh, ll_, m, kg); break;
            case 4: cov_step<4>(acc, lh, ll_, m, kg); break;
            case 5: cov_step<5>(acc, lh, ll_, m, kg); break;
            case 6: cov_step<6>(acc, lh, ll_, m, kg); break;
            default: cov_step<7>(acc, lh, ll_, m, kg); break;
        }
    }
    atomicAdd(&sums[ch], colsum);
    float* Pb = P + ((size_t)(blockIdx.x * 8 + wave) * 17) * 256;
#pragma unroll
    for (int t = 0; t < 17; ++t)
        *(f32x4*)&Pb[t * 256 + lane * 4] = acc[t];
}

// ---------------- register-resident 32x32 diag factor + triangular inverse ----------------
// Runs on one wave (tid<64). Writes L^{-1} of diag block into Lg's diag block (lower).
__device__ __attribute__((noinline)) void diag_fact(float* __restrict__ Lg, int k0, int tid) {
    if (tid >= 64) return;
    int col = tid & 31;
    float a[32];
#pragma unroll
    for (int i = 0; i < 32; ++i) {
        int ii = (i >= col) ? i : col;
        int jj = (i >= col) ? col : i;
        a[i] = Lg[PAD(k0 + ii) + k0 + jj];
    }
    float drec = 0.f;
#pragma unroll
    for (int k = 0; k < 32; ++k) {
        float akk = bcastf(a[k], k);
        float rinv = rsqrtf(akk);
        float myl = a[k] * rinv;
        bool up = (col > k);
#pragma unroll
        for (int i = k + 1; i < 32; ++i) {
            float lik = bcastf(a[i], k) * rinv;
            if (up) a[i] -= lik * myl;
            if (col == k) a[i] = lik;
        }
        if (col == k) { a[k] = akk * rinv; drec = rinv; }
    }
    float xv[32];
#pragma unroll
    for (int i = 0; i < 32; ++i) xv[i] = (col == i) ? 1.f : 0.f;
#pragma unroll
    for (int i = 0; i < 32; ++i) {
        float di = bcastf(drec, i);
        float xi = xv[i] * di;
        xv[i] = xi;
#pragma unroll
        for (int j = i + 1; j < 32; ++j) {
            float lji = bcastf(a[j], i);
            xv[j] -= lji * xi;
        }
    }
    if (tid < 32) {
#pragma unroll
        for (int i = 0; i < 32; ++i)
            if (i >= col) Lg[PAD(k0 + i) + k0 + col] = xv[i];
    }
}

// ---------------- K3: cooperative init + blocked Cholesky + blocked inverse ----------------
__global__ __launch_bounds__(256) void k_factco(const float* __restrict__ P,
                                                const float* __restrict__ sums,
                                                const float* __restrict__ gamma,
                                                float* __restrict__ Lg,
                                                unsigned short* __restrict__ Wphi,
                                                unsigned short* __restrict__ Wplo,
                                                float* __restrict__ biasacc) {
    cg::grid_group grid = cg::this_grid();
    __shared__ __align__(16) float DS[1152];       // 32x36 Dinv (panel phase)
    __shared__ __align__(16) float As[32][36];     // trail staging
    __shared__ __align__(16) float Bs[32][36];
    __shared__ __align__(16) float Wcol[256][36];  // inv phase
    __shared__ __align__(16) float Ls[32][36];
    __shared__ __align__(16) float Tst[32][36];
    int tid = threadIdx.x, bid = blockIdx.x;

    // ---- phase 0: sum P partials -> covariance triangle ----
    for (int chunk = bid; chunk < 136; chunk += 28) {
        int W = chunk / 17, t = chunk % 17;
        int R  = (t <= W) ? W : 15 - W;
        int tj = (t <= W) ? t : t - W - 1;
        int lane = tid >> 2, q = tid & 3;
        int kg = lane >> 4, m = lane & 15;
        int i = R * 16 + kg * 4 + q;
        int j = tj * 16 + m;
        float s = 0.f;
        const float* p = P + (size_t)chunk * 256 + tid;
#pragma unroll 4
        for (int b = 0; b < NBLK; ++b)
            s += p[(size_t)b * 8 * 17 * 256];
        if (j <= i) {
            const float scale = (1.f - EPSV) / ((float)NROWS - 1.f);
            float v = (s - sums[i] * sums[j] * (1.f / (float)NROWS)) * scale;
            if (i == j) v += EPSV;
            Lg[PAD(i) + j] = v;
        }
    }
    grid.sync();

    // ---- diag factor kb=0 ----
    if (bid == 0) diag_fact(Lg, 0, tid);
    grid.sync();

    for (int kb = 0; kb < 7; ++kb) {
        int k0 = kb * 32;

        // ---- panel solve: L21 = A21 * Dinv^T, 8 rows per block ----
        {
            int r = tid >> 3, cq = (tid & 7) * 4;   // stage Dinv (zero upper) from Lg diag
            const float* row = &Lg[PAD(k0 + r) + k0];
            float4 v;
            v.x = (cq     <= r) ? row[cq]     : 0.f;
            v.y = (cq + 1 <= r) ? row[cq + 1] : 0.f;
            v.z = (cq + 2 <= r) ? row[cq + 2] : 0.f;
            v.w = (cq + 3 <= r) ? row[cq + 3] : 0.f;
            *(float4*)&DS[r * 36 + cq] = v;
        }
        __syncthreads();
        {
            int mrows = 224 - k0;
            int rl = tid >> 1, g = tid & 1;
            int r = bid * 8 + rl;
            if (rl < 8 && r < mrows) {
                int abase = PAD(k0 + 32 + r) + k0;
                float4 av[8];
#pragma unroll
                for (int q = 0; q < 8; ++q) av[q] = *(const float4*)&Lg[abase + q * 4];
#pragma unroll
                for (int tgrp = 0; tgrp < 4; ++tgrp) {
                    int cbase = g * 16 + tgrp * 4;
                    float rv[4];
#pragma unroll
                    for (int cc = 0; cc < 4; ++cc) {
                        const float* drow = &DS[(cbase + cc) * 36];
                        float s = 0.f;
#pragma unroll
                        for (int q = 0; q < 8; ++q) {
                            float4 d4 = *(const float4*)&drow[q * 4];
                            s += av[q].x*d4.x + av[q].y*d4.y + av[q].z*d4.z + av[q].w*d4.w;
                        }
                        rv[cc] = s;
                    }
                    float4 res; res.x = rv[0]; res.y = rv[1]; res.z = rv[2]; res.w = rv[3];
                    *(float4*)&Lg[abase + cbase] = res;
                }
            }
        }
        grid.sync();

        // ---- trailing update: one 32x32 pair per block; block 0 then factors diag(kb+1) ----
        {
            int npairs = TRI(7 - kb);
            if (bid < npairs) {
                int p = bid;
                int a2 = 0;
                while (TRI(a2 + 1) <= p) ++a2;
                int b2 = p - TRI(a2);
                int ib2 = kb + 1 + a2, jb2 = kb + 1 + b2;
                {
                    int r = tid >> 3, cq = (tid & 7) * 4;
                    *(float4*)&As[r][cq] = *(const float4*)&Lg[PAD(ib2 * 32 + r) + k0 + cq];
                    *(float4*)&Bs[r][cq] = *(const float4*)&Lg[PAD(jb2 * 32 + r) + k0 + cq];
                }
                __syncthreads();
                int r2 = (tid >> 4) * 2, c2 = (tid & 15) * 2;
                float t00 = 0, t01 = 0, t10 = 0, t11 = 0;
#pragma unroll 8
                for (int q = 0; q < 32; ++q) {
                    float a0 = As[r2][q], a1 = As[r2 + 1][q];
                    float b0 = Bs[c2][q], b1 = Bs[c2 + 1][q];
                    t00 += a0 * b0; t01 += a0 * b1;
                    t10 += a1 * b0; t11 += a1 * b1;
                }
                int gi = ib2 * 32 + r2, gj = jb2 * 32 + c2;
                if (ib2 != jb2) {
                    float* p0 = &Lg[PAD(gi) + gj];
                    float* p1 = &Lg[PAD(gi + 1) + gj];
                    p0[0] -= t00; p0[1] -= t01;
                    p1[0] -= t10; p1[1] -= t11;
                } else {
                    if (c2     <= r2    ) Lg[PAD(gi) + gj]         -= t00;
                    if (c2 + 1 <= r2    ) Lg[PAD(gi) + gj + 1]     -= t01;
                    if (c2     <= r2 + 1) Lg[PAD(gi + 1) + gj]     -= t10;
                    if (c2 + 1 <= r2 + 1) Lg[PAD(gi + 1) + gj + 1] -= t11;
                }
                if (bid == 0) {
                    __syncthreads();          // pair 0 = (kb+1,kb+1) updates visible in-block
                    diag_fact(Lg, (kb + 1) * 32, tid);
                }
            }
        }
        grid.sync();
    }

    // ---- blocked inverse + packed bf16 epilogue (blocks 0..7) ----
    if (bid < 8) {
        int jbb = bid;
        int j0 = jbb * 32;
        {
            int r = tid >> 3, cq = (tid & 7) * 4;
            const float* row = &Lg[PAD(j0 + r) + j0];
            float4 v;
            v.x = (cq     <= r) ? row[cq]     : 0.f;
            v.y = (cq + 1 <= r) ? row[cq + 1] : 0.f;
            v.z = (cq + 2 <= r) ? row[cq + 2] : 0.f;
            v.w = (cq + 3 <= r) ? row[cq + 3] : 0.f;
            *(float4*)&Wcol[j0 + r][cq] = v;
        }
        __syncthreads();

        int r2 = (tid >> 4) * 2, c2 = (tid & 15) * 2;
        for (int ib = jbb + 1; ib < 8; ++ib) {
            int i0 = ib * 32;
            float t00 = 0, t01 = 0, t10 = 0, t11 = 0;
            for (int kb = jbb; kb < ib; ++kb) {
                __syncthreads();
                {
                    int r = tid >> 3, cq = (tid & 7) * 4;
                    *(float4*)&Ls[r][cq] = *(const float4*)&Lg[PAD(i0 + r) + kb * 32 + cq];
                }
                __syncthreads();
                int kw = kb * 32;
#pragma unroll 8
                for (int q = 0; q < 32; ++q) {
                    float l0 = Ls[r2][q], l1 = Ls[r2 + 1][q];
                    float w0 = Wcol[kw + q][c2], w1 = Wcol[kw + q][c2 + 1];
                    t00 += l0 * w0; t01 += l0 * w1;
                    t10 += l1 * w0; t11 += l1 * w1;
                }
            }
            __syncthreads();
            Tst[r2][c2] = t00;     Tst[r2][c2 + 1] = t01;
            Tst[r2 + 1][c2] = t10; Tst[r2 + 1][c2 + 1] = t11;
            {
                int r = tid >> 3, cq = (tid & 7) * 4;
                const float* row = &Lg[PAD(i0 + r) + i0];
                float4 v;
                v.x = (cq     <= r) ? row[cq]     : 0.f;
                v.y = (cq + 1 <= r) ? row[cq + 1] : 0.f;
                v.z = (cq + 2 <= r) ? row[cq + 2] : 0.f;
                v.w = (cq + 3 <= r) ? row[cq + 3] : 0.f;
                *(float4*)&Ls[r][cq] = v;
            }
            __syncthreads();
            float w00 = 0, w01 = 0, w10 = 0, w11 = 0;
#pragma unroll 8
            for (int q = 0; q < 32; ++q) {
                float d0 = Ls[r2][q], d1 = Ls[r2 + 1][q];
                float tq0 = Tst[q][c2], tq1 = Tst[q][c2 + 1];
                w00 += d0 * tq0; w01 += d0 * tq1;
                w10 += d1 * tq0; w11 += d1 * tq1;
            }
            Wcol[i0 + r2][c2] = -w00;     Wcol[i0 + r2][c2 + 1] = -w01;
            Wcol[i0 + r2 + 1][c2] = -w10; Wcol[i0 + r2 + 1][c2 + 1] = -w11;
        }
        __syncthreads();

        {
            int r = tid;
            if (r >= j0) {
                float s = 0.f;
#pragma unroll 8
                for (int c = 0; c < 32; ++c)
                    s += Wcol[r][c] * sums[j0 + c];
                atomicAdd(&biasacc[r], s * (1.f / (float)NROWS));
            }
        }
        for (int pi = tid; pi < 1024; pi += 256) {
            int jt = pi >> 6, l = pi & 63;
            int row = jt * 16 + (l & 15);
            int cb = (l >> 4) * 8;
            float g = (row >= j0) ? gamma[row] : 0.f;
            u16x4 h0, h1, lo0, lo1;
#pragma unroll
            for (int j = 0; j < 8; ++j) {
                float v = (row >= j0) ? g * Wcol[row][cb + j] : 0.f;
                unsigned b = __float_as_uint(v);
                unsigned short hi = (unsigned short)(b >> 16);
                float lf = v - __uint_as_float(b & 0xFFFF0000u);
                unsigned short lo = (unsigned short)(__float_as_uint(lf) >> 16);
                if (j < 4) { h0[j] = hi; lo0[j] = lo; }
                else       { h1[j - 4] = hi; lo1[j - 4] = lo; }
            }
            size_t base = ((size_t)(jt * 8 + jbb) * 64 + l) * 8;
            *(u16x4*)&Wphi[base]     = h0;
            *(u16x4*)&Wphi[base + 4] = h1;
            *(u16x4*)&Wplo[base]     = lo0;
            *(u16x4*)&Wplo[base + 4] = lo1;
        }
    }
}

// ---------------- K4: out = bf16(x) * Wg^T + bias; B staged in LDS per kcg ----------------
__global__ __launch_bounds__(512) void k_apply(const float* __restrict__ x,
                                               const unsigned short* __restrict__ Wphi,
                                               const unsigned short* __restrict__ Wplo,
                                               const float* __restrict__ beta,
                                               const float* __restrict__ gamma,
                                               const float* __restrict__ biasacc,
                                               float* __restrict__ out) {
    __shared__ unsigned short Bh[8192];   // 16 KB: one kcg chunk [jt][lane][8]
    __shared__ unsigned short Bl[8192];   // 16 KB
    int tid = threadIdx.x, wave = tid >> 6, lane = tid & 63;
    int m = lane & 15, kg = lane >> 4;
    size_t rbase = (size_t)blockIdx.x * 128 + wave * 16;
    const float* xr = x + (rbase + m) * 256;

    f32x4 acc[16];
#pragma unroll
    for (int t = 0; t < 16; ++t) acc[t] = 0.f;

#pragma unroll
    for (int kcg = 0; kcg < 8; ++kcg) {
        __syncthreads();
#pragma unroll
        for (int v = tid; v < 1024; v += 512) {
            int jt = v >> 6, off = (v & 63) * 8;
            size_t src = (size_t)(jt * 8 + kcg) * 512 + off;
            int dst = jt * 512 + off;
            *(u16x8*)&Bh[dst] = *(const u16x8*)&Wphi[src];
            *(u16x8*)&Bl[dst] = *(const u16x8*)&Wplo[src];
        }
        f32x4 a0 = *(const f32x4*)&xr[kcg * 32 + kg * 8];
        f32x4 a1 = *(const f32x4*)&xr[kcg * 32 + kg * 8 + 4];
        bf16x8 ah;
#pragma unroll
        for (int e = 0; e < 4; ++e) {
            unsigned b0 = __float_as_uint(a0[e]);
            b0 += 0x7FFFu + ((b0 >> 16) & 1u);
            ah[e] = (short)(b0 >> 16);
            unsigned b1 = __float_as_uint(a1[e]);
            b1 += 0x7FFFu + ((b1 >> 16) & 1u);
            ah[4 + e] = (short)(b1 >> 16);
        }
        __syncthreads();
#pragma unroll
        for (int jt = 0; jt < 16; ++jt) {
            bf16x8 bh = *(const bf16x8*)&Bh[jt * 512 + lane * 8];
            bf16x8 bl = *(const bf16x8*)&Bl[jt * 512 + lane * 8];
            acc[jt] = MFMA16(ah, bh, acc[jt], 0, 0, 0);
            acc[jt] = MFMA16(ah, bl, acc[jt], 0, 0, 0);
        }
    }

#pragma unroll
    for (int jt = 0; jt < 16; ++jt) {
        int j = jt * 16 + m;
        float bb = beta[j] - gamma[j] * biasacc[j];
#pragma unroll
        for (int q = 0; q < 4; ++q)
            out[(rbase + kg * 4 + q) * 256 + j] = acc[jt][q] + bb;
    }
}

extern "C" void kernel_launch(void* const* d_in, const int* in_sizes, int n_in,
                              void* d_out, int out_size, void* d_ws, size_t ws_size,
                              hipStream_t stream) {
    const float* x     = (const float*)d_in[0];
    const float* gamma = (const float*)d_in[1];
    const float* beta  = (const float*)d_in[2];
    float* out  = (float*)d_out;
    float* ws   = (float*)d_ws;
    float* sums     = ws;                 // 256
    float* biasacc  = ws + 256;           // 256
    float* Lg       = ws + 512;           // 33280
    float* P        = ws + 33792;         // 224*8*17*256
    unsigned short* Wphi = (unsigned short*)(ws + 7832576);  // 65536 bf16
    unsigned short* Wplo = (unsigned short*)(ws + 7865344);  // 65536 bf16

    hipMemsetAsync(ws, 0, 512 * sizeof(float), stream);
    hipLaunchKernelGGL(k_cov, dim3(NBLK), dim3(512), 0, stream, x, P, sums);
    {
        void* args[] = { (void*)&P, (void*)&sums, (void*)&gamma, (void*)&Lg,
                         (void*)&Wphi, (void*)&Wplo, (void*)&biasacc };
        hipLaunchCooperativeKernel((const void*)k_factco, dim3(28), dim3(256),
                                   args, 0, stream);
    }
    hipLaunchKernelGGL(k_apply, dim3(1568), dim3(512), 0, stream, x, Wphi, Wplo, beta, gamma, biasacc, out);
}

// Round 17
// 526.382 us; speedup vs baseline: 1.2676x; 1.2676x over previous
//
#include <hip/hip_runtime.h>
#include <hip/hip_bf16.h>
#include <math.h>

#define C 256
#define NROWS (64*56*56)   // 200704
#define EPSV 0.001f
#define TRI(i) (((i)*((i)+1))>>1)
#define NBLK 224           // k_cov blocks

typedef __attribute__((ext_vector_type(8))) short bf16x8;
typedef __attribute__((ext_vector_type(4))) float f32x4;
typedef __attribute__((ext_vector_type(4))) unsigned short u16x4;
typedef __attribute__((ext_vector_type(8))) unsigned short u16x8;
#define MFMA16 __builtin_amdgcn_mfma_f32_16x16x32_bf16

// padded packed-lower-triangle layout: row i starts at PAD(i), rows rounded to 4 floats
__device__ __forceinline__ int PAD(int i) {
    int a = i >> 2, b = i & 3;
    return ((a + 1) * (2 * a + b)) << 2;
}

__device__ __forceinline__ float bcastf(float v, int l) {
    return __int_as_float(__builtin_amdgcn_readlane(__float_as_int(v), l));
}

__device__ __forceinline__ void split2(float v0, float v1, unsigned& hi, unsigned& lo) {
    unsigned b0 = __float_as_uint(v0), b1 = __float_as_uint(v1);
    hi = (b0 >> 16) | (b1 & 0xFFFF0000u);
    float l0 = v0 - __uint_as_float(b0 & 0xFFFF0000u);
    float l1 = v1 - __uint_as_float(b1 & 0xFFFF0000u);
    lo = (__float_as_uint(l0) >> 16) | (__float_as_uint(l1) & 0xFFFF0000u);
}

// ws layout (floats):
//  [0,256)              : channel sums
//  [256,512)            : biasacc
//  [512,33792)          : Lg  (cov -> diag blocks := Dinv; off-diag stays raw)
//  [33792,7832576)      : P   = per-block cov partials [224][8][17][256]
//  [7832576,+32768)     : Wphi
//  [7865344,+32768)     : Wplo
//  [7898112,+65536)     : Pan = persisted panel blocks [8][256][32]

// ---------------- K2: S = X^T X via bf16-split MFMA, partials to P (no atomics) ----------------
template<int W>
__device__ __forceinline__ void cov_step(f32x4* acc, const unsigned* lh, const unsigned* ll,
                                         int m, int kg) {
    constexpr int R0 = W, R1 = 15 - W;
    constexpr int O1 = W + 1;
    bf16x8 ah[2], al[2];
    {
        int r0 = R0 * 16 + m, r1 = R1 * 16 + m;
        int o0 = r0 * 20 + ((kg ^ ((r0 >> 3) & 3)) << 2);
        int o1 = r1 * 20 + ((kg ^ ((r1 >> 3) & 3)) << 2);
        ah[0] = *(const bf16x8*)&lh[o0]; al[0] = *(const bf16x8*)&ll[o0];
        ah[1] = *(const bf16x8*)&lh[o1]; al[1] = *(const bf16x8*)&ll[o1];
    }
#pragma unroll
    for (int c = 0; c <= R1; ++c) {
        int rb = c * 16 + m;
        int ob = rb * 20 + ((kg ^ ((rb >> 3) & 3)) << 2);
        bf16x8 bh = *(const bf16x8*)&lh[ob];
        bf16x8 bl = *(const bf16x8*)&ll[ob];
        if (c <= R0) {
            acc[c] = MFMA16(ah[0], bh, acc[c], 0, 0, 0);
            acc[c] = MFMA16(ah[0], bl, acc[c], 0, 0, 0);
            acc[c] = MFMA16(al[0], bh, acc[c], 0, 0, 0);
        }
        {
            acc[O1 + c] = MFMA16(ah[1], bh, acc[O1 + c], 0, 0, 0);
            acc[O1 + c] = MFMA16(ah[1], bl, acc[O1 + c], 0, 0, 0);
            acc[O1 + c] = MFMA16(al[1], bh, acc[O1 + c], 0, 0, 0);
        }
    }
}

__global__ __launch_bounds__(512, 4) void k_cov(const float* __restrict__ x,
                                                float* __restrict__ P,
                                                float* __restrict__ sums) {
    __shared__ unsigned lh[256 * 20];
    __shared__ unsigned ll_[256 * 20];
    int tid = threadIdx.x, wave = tid >> 6, lane = tid & 63;
    int m = lane & 15, kg = lane >> 4;
    int ch = tid & 255, half = tid >> 8;
    const float* xc = x + (size_t)blockIdx.x * 896 * 256 + ch;
    f32x4 acc[17];
#pragma unroll
    for (int t = 0; t < 17; ++t) acc[t] = 0.f;
    float colsum = 0.f;
    int swkey = (ch >> 3) & 3;

    for (int it = 0; it < 28; ++it) {
        __syncthreads();
        const float* xr = xc + it * 32 * 256;
#pragma unroll
        for (int j = 0; j < 8; ++j) {
            int rp = half * 8 + j;
            float v0 = xr[(2 * rp) * 256];
            float v1 = xr[(2 * rp + 1) * 256];
            colsum += v0 + v1;
            unsigned h, l;
            split2(v0, v1, h, l);
            int idx = ch * 20 + ((((rp >> 2) ^ swkey) << 2) | (rp & 3));
            lh[idx] = h;
            ll_[idx] = l;
        }
        __syncthreads();
        switch (wave) {
            case 0: cov_step<0>(acc, lh, ll_, m, kg); break;
            case 1: cov_step<1>(acc, lh, ll_, m, kg); break;
            case 2: cov_step<2>(acc, lh, ll_, m, kg); break;
            case 3: cov_step<3>(acc, lh, ll_, m, kg); break;
            case 4: cov_step<4>(acc, lh, ll_, m, kg); break;
            case 5: cov_step<5>(acc, lh, ll_, m, kg); break;
            case 6: cov_step<6>(acc, lh, ll_, m, kg); break;
            default: cov_step<7>(acc, lh, ll_, m, kg); break;
        }
    }
    atomicAdd(&sums[ch], colsum);
    float* Pb = P + ((size_t)(blockIdx.x * 8 + wave) * 17) * 256;
#pragma unroll
    for (int t = 0; t < 17; ++t)
        *(f32x4*)&Pb[t * 256 + lane * 4] = acc[t];
}

// ---------------- K3a: sum P partials -> covariance triangle ----------------
__global__ __launch_bounds__(256) void k_init(const float* __restrict__ P,
                                              const float* __restrict__ sums,
                                              float* __restrict__ Lg) {
    int chunk = blockIdx.x;        // W*17 + t
    int W = chunk / 17, t = chunk % 17;
    int R  = (t <= W) ? W : 15 - W;
    int tj = (t <= W) ? t : t - W - 1;
    int tid = threadIdx.x;
    int lane = tid >> 2, q = tid & 3;
    int kg = lane >> 4, m = lane & 15;
    int i = R * 16 + kg * 4 + q;
    int j = tj * 16 + m;

    float s = 0.f;
    const float* p = P + (size_t)(W * 17 + t) * 256 + tid;
#pragma unroll 4
    for (int b = 0; b < NBLK; ++b)
        s += p[(size_t)b * 8 * 17 * 256];

    if (j > i) return;
    const float scale = (1.f - EPSV) / ((float)NROWS - 1.f);
    float v = (s - sums[i] * sums[j] * (1.f / (float)NROWS)) * scale;
    if (i == j) v += EPSV;
    Lg[PAD(i) + j] = v;
}

// ---------------- register-resident 32x32 diag factor + triangular inverse ----------------
// one wave; writes Dinv (lower) into Lg's diag block at k0.
__device__ void diag_fact(float* __restrict__ Lg, int k0, int tid) {
    if (tid >= 64) return;
    int col = tid & 31;
    float a[32];
#pragma unroll
    for (int i = 0; i < 32; ++i) {
        int ii = (i >= col) ? i : col;
        int jj = (i >= col) ? col : i;
        a[i] = Lg[PAD(k0 + ii) + k0 + jj];
    }
    float drec = 0.f;
#pragma unroll
    for (int k = 0; k < 32; ++k) {
        float akk = bcastf(a[k], k);
        float rinv = rsqrtf(akk);
        float myl = a[k] * rinv;
        bool up = (col > k);
#pragma unroll
        for (int i = k + 1; i < 32; ++i) {
            float lik = bcastf(a[i], k) * rinv;
            if (up) a[i] -= lik * myl;
            if (col == k) a[i] = lik;
        }
        if (col == k) { a[k] = akk * rinv; drec = rinv; }
    }
    float xv[32];
#pragma unroll
    for (int i = 0; i < 32; ++i) xv[i] = (col == i) ? 1.f : 0.f;
#pragma unroll
    for (int i = 0; i < 32; ++i) {
        float di = bcastf(drec, i);
        float xi = xv[i] * di;
        xv[i] = xi;
#pragma unroll
        for (int j = i + 1; j < 32; ++j) {
            float lji = bcastf(a[j], i);
            xv[j] -= lji * xi;
        }
    }
    if (tid < 32) {
#pragma unroll
        for (int i = 0; i < 32; ++i)
            if (i >= col) Lg[PAD(k0 + i) + k0 + col] = xv[i];
    }
}

__global__ __launch_bounds__(64) void k_diag0(float* __restrict__ Lg) {
    diag_fact(Lg, 0, threadIdx.x);
}

// ---------------- K3b: per-kb panel+trail, one pair per block, redundant panel ----------------
__global__ __launch_bounds__(256) void k_tp(float* __restrict__ Lg,
                                            float* __restrict__ Pan,
                                            int kb) {
    __shared__ __align__(16) float DS[32 * 36];   // Dinv(kb), zero upper
    __shared__ __align__(16) float As[32][36];    // raw rows ib2
    __shared__ __align__(16) float Bs[32][36];    // raw rows jb2
    __shared__ __align__(16) float Pa[32][36];    // panel rows ib2
    __shared__ __align__(16) float Pb[32][36];    // panel rows jb2
    int tid = threadIdx.x;
    int p = blockIdx.x;
    int a2 = 0;
    while (TRI(a2 + 1) <= p) ++a2;
    int b2 = p - TRI(a2);
    int ib2 = kb + 1 + a2, jb2 = kb + 1 + b2;
    int k0 = kb * 32;
    bool diag = (ib2 == jb2);

    {
        int r = tid >> 3, cq = (tid & 7) * 4;
        // Dinv (zero upper)
        const float* drow = &Lg[PAD(k0 + r) + k0];
        float4 dv;
        dv.x = (cq     <= r) ? drow[cq]     : 0.f;
        dv.y = (cq + 1 <= r) ? drow[cq + 1] : 0.f;
        dv.z = (cq + 2 <= r) ? drow[cq + 2] : 0.f;
        dv.w = (cq + 3 <= r) ? drow[cq + 3] : 0.f;
        *(float4*)&DS[r * 36 + cq] = dv;
        // raw panel-column rows
        *(float4*)&As[r][cq] = *(const float4*)&Lg[PAD(ib2 * 32 + r) + k0 + cq];
        *(float4*)&Bs[r][cq] = *(const float4*)&Lg[PAD(jb2 * 32 + r) + k0 + cq];
    }
    __syncthreads();

    int r2 = (tid >> 4) * 2, c2 = (tid & 15) * 2;
    // panel: Pa = As * Dinv^T, Pb = Bs * Dinv^T
    {
        float pa00 = 0, pa01 = 0, pa10 = 0, pa11 = 0;
        float pb00 = 0, pb01 = 0, pb10 = 0, pb11 = 0;
#pragma unroll 8
        for (int q = 0; q < 32; ++q) {
            float d0 = DS[c2 * 36 + q], d1 = DS[(c2 + 1) * 36 + q];
            float a0 = As[r2][q], a1 = As[r2 + 1][q];
            float b0 = Bs[r2][q], b1 = Bs[r2 + 1][q];
            pa00 += a0 * d0; pa01 += a0 * d1;
            pa10 += a1 * d0; pa11 += a1 * d1;
            pb00 += b0 * d0; pb01 += b0 * d1;
            pb10 += b1 * d0; pb11 += b1 * d1;
        }
        Pa[r2][c2] = pa00;     Pa[r2][c2 + 1] = pa01;
        Pa[r2 + 1][c2] = pa10; Pa[r2 + 1][c2 + 1] = pa11;
        Pb[r2][c2] = pb00;     Pb[r2][c2 + 1] = pb01;
        Pb[r2 + 1][c2] = pb10; Pb[r2 + 1][c2 + 1] = pb11;
    }
    __syncthreads();

    // diagonal pair persists panel rows for k_inv
    if (diag) {
        int r = tid >> 3, cq = (tid & 7) * 4;
        *(float4*)&Pan[(size_t)kb * 8192 + (ib2 * 32 + r) * 32 + cq] =
            *(const float4*)&Pa[r][cq];
    }

    // trail: Lg(ib2,jb2) -= Pa * Pb^T
    {
        float t00 = 0, t01 = 0, t10 = 0, t11 = 0;
#pragma unroll 8
        for (int q = 0; q < 32; ++q) {
            float a0 = Pa[r2][q], a1 = Pa[r2 + 1][q];
            float b0 = Pb[c2][q], b1 = Pb[c2 + 1][q];
            t00 += a0 * b0; t01 += a0 * b1;
            t10 += a1 * b0; t11 += a1 * b1;
        }
        int gi = ib2 * 32 + r2, gj = jb2 * 32 + c2;
        if (!diag) {
            float* p0 = &Lg[PAD(gi) + gj];
            float* p1 = &Lg[PAD(gi + 1) + gj];
            p0[0] -= t00; p0[1] -= t01;
            p1[0] -= t10; p1[1] -= t11;
        } else {
            if (c2     <= r2    ) Lg[PAD(gi) + gj]         -= t00;
            if (c2 + 1 <= r2    ) Lg[PAD(gi) + gj + 1]     -= t01;
            if (c2     <= r2 + 1) Lg[PAD(gi + 1) + gj]     -= t10;
            if (c2 + 1 <= r2 + 1) Lg[PAD(gi + 1) + gj + 1] -= t11;
        }
    }

    // block 0 owns pair (kb+1,kb+1): factor next diag block in-block
    if (p == 0) {
        __syncthreads();
        diag_fact(Lg, k0 + 32, tid);
    }
}

// ---------------- K3c: blocked inverse (off-diag L from Pan) + bf16 epilogue ----------------
__global__ __launch_bounds__(256) void k_inv(const float* __restrict__ Lg,
                                             const float* __restrict__ Pan,
                                             const float* __restrict__ sums,
                                             const float* __restrict__ gamma,
                                             unsigned short* __restrict__ Wphi,
                                             unsigned short* __restrict__ Wplo,
                                             float* __restrict__ biasacc) {
    __shared__ __align__(16) float Wcol[256][36];
    __shared__ __align__(16) float Ls[32][36];
    __shared__ __align__(16) float Tst[32][36];
    int jbb = blockIdx.x;      // 0..7 == kcg
    int tid = threadIdx.x;
    int j0 = jbb * 32;

    {
        int r = tid >> 3, cq = (tid & 7) * 4;
        const float* row = &Lg[PAD(j0 + r) + j0];
        float4 v;
        v.x = (cq     <= r) ? row[cq]     : 0.f;
        v.y = (cq + 1 <= r) ? row[cq + 1] : 0.f;
        v.z = (cq + 2 <= r) ? row[cq + 2] : 0.f;
        v.w = (cq + 3 <= r) ? row[cq + 3] : 0.f;
        *(float4*)&Wcol[j0 + r][cq] = v;
    }
    __syncthreads();

    int r2 = (tid >> 4) * 2, c2 = (tid & 15) * 2;
    for (int ib = jbb + 1; ib < 8; ++ib) {
        int i0 = ib * 32;
        float t00 = 0, t01 = 0, t10 = 0, t11 = 0;
        for (int kb = jbb; kb < ib; ++kb) {
            __syncthreads();
            {
                int r = tid >> 3, cq = (tid & 7) * 4;
                *(float4*)&Ls[r][cq] =
                    *(const float4*)&Pan[(size_t)kb * 8192 + (i0 + r) * 32 + cq];
            }
            __syncthreads();
            int kw = kb * 32;
#pragma unroll 8
            for (int q = 0; q < 32; ++q) {
                float l0 = Ls[r2][q], l1 = Ls[r2 + 1][q];
                float w0 = Wcol[kw + q][c2], w1 = Wcol[kw + q][c2 + 1];
                t00 += l0 * w0; t01 += l0 * w1;
                t10 += l1 * w0; t11 += l1 * w1;
            }
        }
        __syncthreads();
        Tst[r2][c2] = t00;     Tst[r2][c2 + 1] = t01;
        Tst[r2 + 1][c2] = t10; Tst[r2 + 1][c2 + 1] = t11;
        {
            int r = tid >> 3, cq = (tid & 7) * 4;
            const float* row = &Lg[PAD(i0 + r) + i0];
            float4 v;
            v.x = (cq     <= r) ? row[cq]     : 0.f;
            v.y = (cq + 1 <= r) ? row[cq + 1] : 0.f;
            v.z = (cq + 2 <= r) ? row[cq + 2] : 0.f;
            v.w = (cq + 3 <= r) ? row[cq + 3] : 0.f;
            *(float4*)&Ls[r][cq] = v;
        }
        __syncthreads();
        float w00 = 0, w01 = 0, w10 = 0, w11 = 0;
#pragma unroll 8
        for (int q = 0; q < 32; ++q) {
            float d0 = Ls[r2][q], d1 = Ls[r2 + 1][q];
            float tq0 = Tst[q][c2], tq1 = Tst[q][c2 + 1];
            w00 += d0 * tq0; w01 += d0 * tq1;
            w10 += d1 * tq0; w11 += d1 * tq1;
        }
        Wcol[i0 + r2][c2] = -w00;     Wcol[i0 + r2][c2 + 1] = -w01;
        Wcol[i0 + r2 + 1][c2] = -w10; Wcol[i0 + r2 + 1][c2 + 1] = -w11;
    }
    __syncthreads();

    {
        int r = tid;
        if (r >= j0) {
            float s = 0.f;
#pragma unroll 8
            for (int c = 0; c < 32; ++c)
                s += Wcol[r][c] * sums[j0 + c];
            atomicAdd(&biasacc[r], s * (1.f / (float)NROWS));
        }
    }
    for (int pi = tid; pi < 1024; pi += 256) {
        int jt = pi >> 6, l = pi & 63;
        int row = jt * 16 + (l & 15);
        int cb = (l >> 4) * 8;
        float g = (row >= j0) ? gamma[row] : 0.f;
        u16x4 h0, h1, lo0, lo1;
#pragma unroll
        for (int j = 0; j < 8; ++j) {
            float v = (row >= j0) ? g * Wcol[row][cb + j] : 0.f;
            unsigned b = __float_as_uint(v);
            unsigned short hi = (unsigned short)(b >> 16);
            float lf = v - __uint_as_float(b & 0xFFFF0000u);
            unsigned short lo = (unsigned short)(__float_as_uint(lf) >> 16);
            if (j < 4) { h0[j] = hi; lo0[j] = lo; }
            else       { h1[j - 4] = hi; lo1[j - 4] = lo; }
        }
        size_t base = ((size_t)(jt * 8 + jbb) * 64 + l) * 8;
        *(u16x4*)&Wphi[base]     = h0;
        *(u16x4*)&Wphi[base + 4] = h1;
        *(u16x4*)&Wplo[base]     = lo0;
        *(u16x4*)&Wplo[base + 4] = lo1;
    }
}

// ---------------- K4: out = bf16(x) * Wg^T + bias; B staged in LDS per kcg ----------------
__global__ __launch_bounds__(512) void k_apply(const float* __restrict__ x,
                                               const unsigned short* __restrict__ Wphi,
                                               const unsigned short* __restrict__ Wplo,
                                               const float* __restrict__ beta,
                                               const float* __restrict__ gamma,
                                               const float* __restrict__ biasacc,
                                               float* __restrict__ out) {
    __shared__ unsigned short Bh[8192];
    __shared__ unsigned short Bl[8192];
    int tid = threadIdx.x, wave = tid >> 6, lane = tid & 63;
    int m = lane & 15, kg = lane >> 4;
    size_t rbase = (size_t)blockIdx.x * 128 + wave * 16;
    const float* xr = x + (rbase + m) * 256;

    f32x4 acc[16];
#pragma unroll
    for (int t = 0; t < 16; ++t) acc[t] = 0.f;

#pragma unroll
    for (int kcg = 0; kcg < 8; ++kcg) {
        __syncthreads();
#pragma unroll
        for (int v = tid; v < 1024; v += 512) {
            int jt = v >> 6, off = (v & 63) * 8;
            size_t src = (size_t)(jt * 8 + kcg) * 512 + off;
            int dst = jt * 512 + off;
            *(u16x8*)&Bh[dst] = *(const u16x8*)&Wphi[src];
            *(u16x8*)&Bl[dst] = *(const u16x8*)&Wplo[src];
        }
        f32x4 a0 = *(const f32x4*)&xr[kcg * 32 + kg * 8];
        f32x4 a1 = *(const f32x4*)&xr[kcg * 32 + kg * 8 + 4];
        bf16x8 ah;
#pragma unroll
        for (int e = 0; e < 4; ++e) {
            unsigned b0 = __float_as_uint(a0[e]);
            b0 += 0x7FFFu + ((b0 >> 16) & 1u);
            ah[e] = (short)(b0 >> 16);
            unsigned b1 = __float_as_uint(a1[e]);
            b1 += 0x7FFFu + ((b1 >> 16) & 1u);
            ah[4 + e] = (short)(b1 >> 16);
        }
        __syncthreads();
#pragma unroll
        for (int jt = 0; jt < 16; ++jt) {
            bf16x8 bh = *(const bf16x8*)&Bh[jt * 512 + lane * 8];
            bf16x8 bl = *(const bf16x8*)&Bl[jt * 512 + lane * 8];
            acc[jt] = MFMA16(ah, bh, acc[jt], 0, 0, 0);
            acc[jt] = MFMA16(ah, bl, acc[jt], 0, 0, 0);
        }
    }

#pragma unroll
    for (int jt = 0; jt < 16; ++jt) {
        int j = jt * 16 + m;
        float bb = beta[j] - gamma[j] * biasacc[j];
#pragma unroll
        for (int q = 0; q < 4; ++q)
            out[(rbase + kg * 4 + q) * 256 + j] = acc[jt][q] + bb;
    }
}

extern "C" void kernel_launch(void* const* d_in, const int* in_sizes, int n_in,
                              void* d_out, int out_size, void* d_ws, size_t ws_size,
                              hipStream_t stream) {
    const float* x     = (const float*)d_in[0];
    const float* gamma = (const float*)d_in[1];
    const float* beta  = (const float*)d_in[2];
    float* out  = (float*)d_out;
    float* ws   = (float*)d_ws;
    float* sums     = ws;                 // 256
    float* biasacc  = ws + 256;           // 256
    float* Lg       = ws + 512;           // 33280
    float* P        = ws + 33792;         // 224*8*17*256
    unsigned short* Wphi = (unsigned short*)(ws + 7832576);  // 65536 bf16
    unsigned short* Wplo = (unsigned short*)(ws + 7865344);  // 65536 bf16
    float* Pan      = ws + 7898112;       // 8*256*32 = 65536

    hipMemsetAsync(ws, 0, 512 * sizeof(float), stream);
    hipLaunchKernelGGL(k_cov, dim3(NBLK), dim3(512), 0, stream, x, P, sums);
    hipLaunchKernelGGL(k_init, dim3(136), dim3(256), 0, stream, P, sums, Lg);
    hipLaunchKernelGGL(k_diag0, dim3(1), dim3(64), 0, stream, Lg);
    for (int kb = 0; kb < 7; ++kb)
        hipLaunchKernelGGL(k_tp, dim3(TRI(7 - kb)), dim3(256), 0, stream, Lg, Pan, kb);
    hipLaunchKernelGGL(k_inv, dim3(8), dim3(256), 0, stream, Lg, Pan, sums, gamma, Wphi, Wplo, biasacc);
    hipLaunchKernelGGL(k_apply, dim3(1568), dim3(512), 0, stream, x, Wphi, Wplo, beta, gamma, biasacc, out);
}